// Round 3
// baseline (136.104 us; speedup 1.0000x reference)
//
#include <hip/hip_runtime.h>
#include <math.h>

#define NELEM  8388608
#define GRID   2048
#define BLOCK  256
#define NVEC   (NELEM / 4)          // 2097152
#define STRIDE (GRID * BLOCK)       // 524288 -> exactly 4 vec4 groups per thread

// Fused streaming reduction + last-block finalize.
// - 512-entry float4 LDS table indexed by (t<<1)|risk:
//     risk=1 (loglik): val = -1*lam + t*ll - lgamma(t+1)
//     risk=0 (surv):   val = (t+1)*lam - (t(t+1)/2)*ll + (t+1)+csum[t]
//   so val = c.x*lam + c.y*ll + c.z for both.
// - counter is zeroed by a hipMemsetAsync node before this kernel each call,
//   so finisher = (old == GRID-1) is the true last-arriving block.
__global__ __launch_bounds__(BLOCK) void loss_fused(
    const float4* __restrict__ lam4,
    const int4*   __restrict__ tgt4,
    const int4*   __restrict__ risk4,
    double*       __restrict__ partials,
    unsigned int* __restrict__ counter,
    float*        __restrict__ out)
{
    __shared__ float4 tab[512];
    __shared__ float  woff[4];
    __shared__ double wsum[4];
    __shared__ int    finisher;

    const int tid  = threadIdx.x;
    const int lane = tid & 63;
    const int wid  = tid >> 6;

    // ---- build combined coefficient table (one t per thread) ----
    {
        float tf = (float)tid;
        float v  = lgammaf(tf + 1.0f);      // ln(t!)
        float scan = v;                      // inclusive wave scan
        #pragma unroll
        for (int d = 1; d < 64; d <<= 1) {
            float n = __shfl_up(scan, d, 64);
            if (lane >= d) scan += n;
        }
        if (lane == 63) woff[wid] = scan;
        __syncthreads();
        float off = 0.f;
        for (int w = 0; w < wid; ++w) off += woff[w];
        float csum = scan + off;             // cumsum of ln(j!) up to t
        tab[(tid << 1) | 1] = make_float4(-1.0f, tf, -v, 0.0f);
        tab[(tid << 1)]     = make_float4(tf + 1.0f,
                                          -tf * (tf + 1.0f) * 0.5f,
                                          (tf + 1.0f) + csum, 0.0f);
    }
    __syncthreads();

    // ---- issue loads grouped so GROUP0's operands are the oldest in flight ----
    const int base = blockIdx.x * BLOCK + tid;
    float4 L0 = lam4[base];
    int4   T0 = tgt4[base];
    int4   R0 = risk4[base];
    float4 L1 = lam4[base + STRIDE];
    int4   T1 = tgt4[base + STRIDE];
    int4   R1 = risk4[base + STRIDE];
    float4 L2 = lam4[base + 2 * STRIDE];
    int4   T2 = tgt4[base + 2 * STRIDE];
    int4   R2 = risk4[base + 2 * STRIDE];
    float4 L3 = lam4[base + 3 * STRIDE];
    int4   T3 = tgt4[base + 3 * STRIDE];
    int4   R3 = risk4[base + 3 * STRIDE];

    double acc = 0.0;
    #define ONE(la_, t_, r_, g_) {                                   \
        float  la = (la_);                                           \
        float4 c  = tab[((t_) << 1) | (r_)];                         \
        float  ll = __logf(la);                                      \
        g_ += fmaf(c.x, la, fmaf(c.y, ll, c.z));                     \
    }
    #define GROUP(L, T, R) {                                         \
        float g = 0.f;                                               \
        ONE(L.x, T.x, R.x, g);                                       \
        ONE(L.y, T.y, R.y, g);                                       \
        ONE(L.z, T.z, R.z, g);                                       \
        ONE(L.w, T.w, R.w, g);                                       \
        acc += (double)g;                                            \
    }
    GROUP(L0, T0, R0);
    GROUP(L1, T1, R1);
    GROUP(L2, T2, R2);
    GROUP(L3, T3, R3);
    #undef GROUP
    #undef ONE

    // ---- block reduce (double, fixed order) ----
    #pragma unroll
    for (int d = 32; d > 0; d >>= 1) acc += __shfl_down(acc, d, 64);
    if (lane == 0) wsum[wid] = acc;
    __syncthreads();

    if (tid == 0) {
        double total = wsum[0] + wsum[1] + wsum[2] + wsum[3];
        __hip_atomic_store(&partials[blockIdx.x], total,
                           __ATOMIC_RELEASE, __HIP_MEMORY_SCOPE_AGENT);
        unsigned int old = __hip_atomic_fetch_add(counter, 1u,
                           __ATOMIC_ACQ_REL, __HIP_MEMORY_SCOPE_AGENT);
        finisher = (old == GRID - 1u) ? 1 : 0;
    }
    __syncthreads();

    // ---- last arriving block does the deterministic final reduce ----
    if (finisher) {
        double s = 0.0;
        #pragma unroll
        for (int i = 0; i < GRID / BLOCK; ++i)       // fixed index order
            s += __hip_atomic_load(&partials[tid + i * BLOCK],
                                   __ATOMIC_RELAXED, __HIP_MEMORY_SCOPE_AGENT);
        #pragma unroll
        for (int d = 32; d > 0; d >>= 1) s += __shfl_down(s, d, 64);
        if (lane == 0) wsum[wid] = s;
        __syncthreads();
        if (tid == 0) {
            double tot = wsum[0] + wsum[1] + wsum[2] + wsum[3];
            out[0] = (float)(-tot / (double)NELEM);
        }
    }
}

extern "C" void kernel_launch(void* const* d_in, const int* in_sizes, int n_in,
                              void* d_out, int out_size, void* d_ws, size_t ws_size,
                              hipStream_t stream)
{
    const float4* lam4  = (const float4*)d_in[0];
    const int4*   tgt4  = (const int4*)d_in[1];
    const int4*   risk4 = (const int4*)d_in[2];
    // layout: [0,4)   counter  (zeroed each call below)
    //         [64,...) partials (2048 doubles; every slot written every call)
    unsigned int* counter  = (unsigned int*)d_ws;
    double*       partials = (double*)((char*)d_ws + 64);
    float*        out      = (float*)d_out;

    hipMemsetAsync(d_ws, 0, 4, stream);   // graph-capturable memset node
    loss_fused<<<GRID, BLOCK, 0, stream>>>(lam4, tgt4, risk4, partials, counter, out);
}

// Round 4
// 68.518 us; speedup vs baseline: 1.9864x; 1.9864x over previous
//
#include <hip/hip_runtime.h>
#include <math.h>

#define NELEM  8388608
#define GRID   2048
#define BLOCK  256
#define NVEC   (NELEM / 4)          // 2097152
#define STRIDE (GRID * BLOCK)       // 524288 -> exactly 4 vec4 groups per thread
#define SCALE  1048576.0            // 2^20 fixed-point scale for int64 accumulation

// Fully fused streaming reduction, single kernel + 16B memset node.
//
// Per element (t = target, r = risk, la = lam):
//   r==1: val = -la + t*ll - lgamma(t+1)            (ll = log la)
//   r==0: val = (t+1)*la - t(t+1)/2*ll + (t+1)+csum[t]
// -> val = a*la + c.x*ll + c.y  with a = r ? -1 : (t+1) (2 VALU ops),
//    c = float2 LDS table[(t<<1)|r] (b64 gather, low bank conflict).
//
// Cross-block combine: fixed-point int64 relaxed atomicAdd (bitwise
// deterministic, no agent-scope acquire/release -> no L2 wb/inv storms,
// which is what made round-2's fused version 9x slower). Ordering
// "my acc-add completed before my arrival tick" via s_waitcnt vmcnt(0)
// between the two relaxed RMWs; last arrival (counter==GRID-1, counter
// zeroed by the memset node each call) reads the total with atomicAdd(,0)
// (coherence-point read) and writes the output.
__global__ __launch_bounds__(BLOCK) void loss_fused(
    const float4* __restrict__ lam4,
    const int4*   __restrict__ tgt4,
    const int4*   __restrict__ risk4,
    unsigned long long* __restrict__ acc_i64,
    unsigned int* __restrict__ counter,
    float*        __restrict__ out)
{
    __shared__ float2 tab[512];
    __shared__ float  woff[4];
    __shared__ double wsum[4];

    const int tid  = threadIdx.x;
    const int lane = tid & 63;
    const int wid  = tid >> 6;

    // ---- build coefficient table (one t per thread) ----
    {
        float tf = (float)tid;
        float v  = lgammaf(tf + 1.0f);       // ln(t!)
        float scan = v;                       // inclusive wave scan
        #pragma unroll
        for (int d = 1; d < 64; d <<= 1) {
            float n = __shfl_up(scan, d, 64);
            if (lane >= d) scan += n;
        }
        if (lane == 63) woff[wid] = scan;
        __syncthreads();
        float off = 0.f;
        for (int w = 0; w < wid; ++w) off += woff[w];
        float csum = scan + off;              // cumsum of ln(j!) up to t
        tab[(tid << 1) | 1] = make_float2(tf, -v);
        tab[(tid << 1)]     = make_float2(-tf * (tf + 1.0f) * 0.5f,
                                          (tf + 1.0f) + csum);
    }
    __syncthreads();

    // ---- streaming reduction (R1-proven loop shape) ----
    double acc = 0.0;
    for (int idx = blockIdx.x * BLOCK + tid; idx < NVEC; idx += STRIDE) {
        float4 L = lam4[idx];
        int4   T = tgt4[idx];
        int4   R = risk4[idx];
        float g = 0.f;
        #define ONE(la_, t_, r_) {                                   \
            float  la = (la_);                                       \
            int    t  = (t_);                                        \
            int    r  = (r_);                                        \
            float  tf = (float)t;                                    \
            float  a  = (r == 1) ? -1.0f : (tf + 1.0f);              \
            float2 c  = tab[(t << 1) | r];                           \
            float  ll = __logf(la);                                  \
            g += fmaf(a, la, fmaf(c.x, ll, c.y));                    \
        }
        ONE(L.x, T.x, R.x);
        ONE(L.y, T.y, R.y);
        ONE(L.z, T.z, R.z);
        ONE(L.w, T.w, R.w);
        #undef ONE
        acc += (double)g;
    }

    // ---- block reduce (double, fixed order) ----
    #pragma unroll
    for (int d = 32; d > 0; d >>= 1) acc += __shfl_down(acc, d, 64);
    if (lane == 0) wsum[wid] = acc;
    __syncthreads();

    if (tid == 0) {
        double total = wsum[0] + wsum[1] + wsum[2] + wsum[3];
        long long scaled = llrint(total * SCALE);
        // relaxed HW atomic; returning form so completion is vmcnt-tracked
        unsigned long long prev = atomicAdd(acc_i64, (unsigned long long)scaled);
        // ensure my acc-add reached the coherence point before arrival tick
        asm volatile("s_waitcnt vmcnt(0)" :: "v"((unsigned int)prev) : "memory");
        unsigned int old = atomicAdd(counter, 1u);
        if (old == GRID - 1u) {
            // true last arrival: all acc-adds complete. Coherent read via RMW.
            unsigned long long tot = atomicAdd(acc_i64, 0ULL);
            double sum = (double)(long long)tot * (1.0 / SCALE);
            out[0] = (float)(-sum / (double)NELEM);
        }
    }
}

extern "C" void kernel_launch(void* const* d_in, const int* in_sizes, int n_in,
                              void* d_out, int out_size, void* d_ws, size_t ws_size,
                              hipStream_t stream)
{
    const float4* lam4  = (const float4*)d_in[0];
    const int4*   tgt4  = (const int4*)d_in[1];
    const int4*   risk4 = (const int4*)d_in[2];
    // ws layout: [0,8) int64 accumulator, [8,12) arrival counter
    unsigned long long* acc_i64 = (unsigned long long*)d_ws;
    unsigned int*       counter = (unsigned int*)((char*)d_ws + 8);
    float*              out     = (float*)d_out;

    hipMemsetAsync(d_ws, 0, 16, stream);   // graph-capturable memset node
    loss_fused<<<GRID, BLOCK, 0, stream>>>(lam4, tgt4, risk4, acc_i64, counter, out);
}

// Round 5
// 28.020 us; speedup vs baseline: 4.8573x; 2.4453x over previous
//
#include <hip/hip_runtime.h>
#include <math.h>

#define NELEM  8388608
#define GRID   2048
#define BLOCK  256
#define NVEC   (NELEM / 4)          // 2097152
#define STRIDE (GRID * BLOCK)       // 524288 -> exactly 4 vec4 groups per thread

// Single fused kernel + one 8KB memset node (zeroes the flags array).
//
// Per element (t = target, r = risk, la = lam, ll = log la):
//   r==1: val = -la + t*ll - lgamma(t+1)
//   r==0: val = (t+1)*la - t(t+1)/2*ll + ((t+1)+csum[t])
// -> val = a*la + c.x*ll + c.y, a = r ? -1 : t+1, c = float2 tab[(t<<1)|r].
//
// Cross-block combine (the R3/R4 lesson: no agent fences, no same-line RMW
// storms): per-block partial + ready flag stored to DISTINCT addresses with
// relaxed agent-scope atomic stores (device-coherent, no L2 maintenance),
// ordered by one s_waitcnt vmcnt(0). Block 0 spin-reads flags (relaxed agent
// loads; deadlock-free: 2047 other block slots keep draining) and reduces
// partials in fixed index order -> bitwise deterministic output.
__global__ __launch_bounds__(BLOCK) void loss_fused(
    const float4* __restrict__ lam4,
    const int4*   __restrict__ tgt4,
    const int4*   __restrict__ risk4,
    unsigned int* __restrict__ flags,          // [GRID], memset 0 each call
    unsigned long long* __restrict__ partials, // [GRID], gated by flags
    float*        __restrict__ out)
{
    __shared__ float2 tab[512];
    __shared__ float  woff[4];
    __shared__ double wsum[4];

    const int tid  = threadIdx.x;
    const int lane = tid & 63;
    const int wid  = tid >> 6;

    // ---- build coefficient table (one t per thread) ----
    {
        float tf = (float)tid;
        float v  = lgammaf(tf + 1.0f);       // ln(t!)
        float scan = v;                       // inclusive wave scan
        #pragma unroll
        for (int d = 1; d < 64; d <<= 1) {
            float n = __shfl_up(scan, d, 64);
            if (lane >= d) scan += n;
        }
        if (lane == 63) woff[wid] = scan;
        __syncthreads();
        float off = 0.f;
        for (int w = 0; w < wid; ++w) off += woff[w];
        float csum = scan + off;              // cumsum of ln(j!) up to t
        tab[(tid << 1) | 1] = make_float2(tf, -v);
        tab[(tid << 1)]     = make_float2(-tf * (tf + 1.0f) * 0.5f,
                                          (tf + 1.0f) + csum);
    }
    __syncthreads();

    // ---- streaming: 4 unrolled groups, loads issued one group ahead ----
    const int base = blockIdx.x * BLOCK + tid;
    double acc = 0.0;

    #define ONE(la_, t_, r_, g_) {                                   \
        float  la = (la_);                                           \
        int    t  = (t_);                                            \
        float  tf = (float)t;                                        \
        float  a  = ((r_) == 1) ? -1.0f : (tf + 1.0f);               \
        float2 c  = tab[(t << 1) | (r_)];                            \
        float  ll = __logf(la);                                      \
        g_ += fmaf(a, la, fmaf(c.x, ll, c.y));                       \
    }
    #define GROUP(L, T, R) {                                         \
        float g = 0.f;                                               \
        ONE(L.x, T.x, R.x, g);                                       \
        ONE(L.y, T.y, R.y, g);                                       \
        ONE(L.z, T.z, R.z, g);                                       \
        ONE(L.w, T.w, R.w, g);                                       \
        acc += (double)g;                                            \
    }

    float4 L0 = lam4[base];              int4 T0 = tgt4[base];              int4 R0 = risk4[base];
    float4 L1 = lam4[base + STRIDE];     int4 T1 = tgt4[base + STRIDE];     int4 R1 = risk4[base + STRIDE];
    GROUP(L0, T0, R0);
    float4 L2 = lam4[base + 2 * STRIDE]; int4 T2 = tgt4[base + 2 * STRIDE]; int4 R2 = risk4[base + 2 * STRIDE];
    GROUP(L1, T1, R1);
    float4 L3 = lam4[base + 3 * STRIDE]; int4 T3 = tgt4[base + 3 * STRIDE]; int4 R3 = risk4[base + 3 * STRIDE];
    GROUP(L2, T2, R2);
    GROUP(L3, T3, R3);
    #undef GROUP
    #undef ONE

    // ---- block reduce (double, fixed order) ----
    #pragma unroll
    for (int d = 32; d > 0; d >>= 1) acc += __shfl_down(acc, d, 64);
    if (lane == 0) wsum[wid] = acc;
    __syncthreads();

    if (tid == 0) {
        double total = wsum[0] + wsum[1] + wsum[2] + wsum[3];
        __hip_atomic_store(&partials[blockIdx.x], (unsigned long long)__double_as_longlong(total),
                           __ATOMIC_RELAXED, __HIP_MEMORY_SCOPE_AGENT);
        // partial must reach the coherence point before the flag does
        asm volatile("s_waitcnt vmcnt(0)" ::: "memory");
        __hip_atomic_store(&flags[blockIdx.x], 1u,
                           __ATOMIC_RELAXED, __HIP_MEMORY_SCOPE_AGENT);
    }

    // ---- block 0: spin-gather all partials, deterministic final reduce ----
    if (blockIdx.x == 0) {
        __syncthreads();   // protect wsum reuse below against fast-running waves
        double s = 0.0;
        #pragma unroll
        for (int i = tid; i < GRID; i += BLOCK) {      // fixed index order per thread
            while (__hip_atomic_load(&flags[i], __ATOMIC_RELAXED,
                                     __HIP_MEMORY_SCOPE_AGENT) == 0u)
                __builtin_amdgcn_s_sleep(1);
            unsigned long long b = __hip_atomic_load(&partials[i], __ATOMIC_RELAXED,
                                                     __HIP_MEMORY_SCOPE_AGENT);
            s += __longlong_as_double((long long)b);
        }
        #pragma unroll
        for (int d = 32; d > 0; d >>= 1) s += __shfl_down(s, d, 64);
        if (lane == 0) wsum[wid] = s;
        __syncthreads();
        if (tid == 0) {
            double tot = wsum[0] + wsum[1] + wsum[2] + wsum[3];
            out[0] = (float)(-tot / (double)NELEM);
        }
    }
}

extern "C" void kernel_launch(void* const* d_in, const int* in_sizes, int n_in,
                              void* d_out, int out_size, void* d_ws, size_t ws_size,
                              hipStream_t stream)
{
    const float4* lam4  = (const float4*)d_in[0];
    const int4*   tgt4  = (const int4*)d_in[1];
    const int4*   risk4 = (const int4*)d_in[2];
    // ws layout: [0, 8192)        flags   (2048 u32) — zeroed each call
    //            [8192, 24576)    partials (2048 u64) — gated by flags
    unsigned int*       flags    = (unsigned int*)d_ws;
    unsigned long long* partials = (unsigned long long*)((char*)d_ws + 8192);
    float*              out      = (float*)d_out;

    hipMemsetAsync(d_ws, 0, 8192, stream);   // graph-capturable memset node
    loss_fused<<<GRID, BLOCK, 0, stream>>>(lam4, tgt4, risk4, flags, partials, out);
}

// Round 6
// 24.503 us; speedup vs baseline: 5.5546x; 1.1435x over previous
//
#include <hip/hip_runtime.h>
#include <math.h>

#define NELEM  8388608
#define GRID   2048
#define BLOCK  256
#define NVEC   (NELEM / 4)          // 2097152
#define STRIDE (GRID * BLOCK)       // 524288 -> exactly 4 vec4 groups per thread

// Two-kernel structure (R1-proven: no ws-init dependence, no atomics, no
// spins — kernel boundary provides cross-block visibility). Main kernel uses
// the R4/R5-verified lean per-element math:
//   r==1: val = -la + t*ll - lgamma(t+1)            (ll = __logf(la))
//   r==0: val = (t+1)*la - t(t+1)/2*ll + ((t+1)+csum[t])
// -> val = a*la + c.x*ll + c.y,  a = r ? -1 : t+1 (2 VALU ops),
//    c = float2 tab[(t<<1)|r]  (one b64 LDS gather per element).
__global__ __launch_bounds__(BLOCK) void loss_main(
    const float4* __restrict__ lam4,
    const int4*   __restrict__ tgt4,
    const int4*   __restrict__ risk4,
    double*       __restrict__ partials)
{
    __shared__ float2 tab[512];
    __shared__ float  woff[4];
    __shared__ double wsum[4];

    const int tid  = threadIdx.x;
    const int lane = tid & 63;
    const int wid  = tid >> 6;

    // ---- build coefficient table (one t per thread) ----
    {
        float tf = (float)tid;
        float v  = lgammaf(tf + 1.0f);       // ln(t!)
        float scan = v;                       // inclusive wave scan
        #pragma unroll
        for (int d = 1; d < 64; d <<= 1) {
            float n = __shfl_up(scan, d, 64);
            if (lane >= d) scan += n;
        }
        if (lane == 63) woff[wid] = scan;
        __syncthreads();
        float off = 0.f;
        for (int w = 0; w < wid; ++w) off += woff[w];
        float csum = scan + off;              // cumsum of ln(j!) up to t
        tab[(tid << 1) | 1] = make_float2(tf, -v);
        tab[(tid << 1)]     = make_float2(-tf * (tf + 1.0f) * 0.5f,
                                          (tf + 1.0f) + csum);
    }
    __syncthreads();

    // ---- streaming: 4 exact-sized groups, loads issued one group ahead ----
    const int base = blockIdx.x * BLOCK + tid;
    double acc = 0.0;

    #define ONE(la_, t_, r_, g_) {                                   \
        float  la = (la_);                                           \
        int    t  = (t_);                                            \
        float  tf = (float)t;                                        \
        float  a  = ((r_) == 1) ? -1.0f : (tf + 1.0f);               \
        float2 c  = tab[(t << 1) | (r_)];                            \
        float  ll = __logf(la);                                      \
        g_ += fmaf(a, la, fmaf(c.x, ll, c.y));                       \
    }
    #define GROUP(L, T, R) {                                         \
        float g = 0.f;                                               \
        ONE(L.x, T.x, R.x, g);                                       \
        ONE(L.y, T.y, R.y, g);                                       \
        ONE(L.z, T.z, R.z, g);                                       \
        ONE(L.w, T.w, R.w, g);                                       \
        acc += (double)g;                                            \
    }

    float4 L0 = lam4[base];              int4 T0 = tgt4[base];              int4 R0 = risk4[base];
    float4 L1 = lam4[base + STRIDE];     int4 T1 = tgt4[base + STRIDE];     int4 R1 = risk4[base + STRIDE];
    GROUP(L0, T0, R0);
    float4 L2 = lam4[base + 2 * STRIDE]; int4 T2 = tgt4[base + 2 * STRIDE]; int4 R2 = risk4[base + 2 * STRIDE];
    GROUP(L1, T1, R1);
    float4 L3 = lam4[base + 3 * STRIDE]; int4 T3 = tgt4[base + 3 * STRIDE]; int4 R3 = risk4[base + 3 * STRIDE];
    GROUP(L2, T2, R2);
    GROUP(L3, T3, R3);
    #undef GROUP
    #undef ONE

    // ---- block reduce (double, fixed order) ----
    #pragma unroll
    for (int d = 32; d > 0; d >>= 1) acc += __shfl_down(acc, d, 64);
    if (lane == 0) wsum[wid] = acc;
    __syncthreads();
    if (tid == 0)
        partials[blockIdx.x] = wsum[0] + wsum[1] + wsum[2] + wsum[3];
}

__global__ __launch_bounds__(256) void loss_finalize(
    const double* __restrict__ partials, float* __restrict__ out)
{
    const int tid  = threadIdx.x;
    const int lane = tid & 63;
    const int wid  = tid >> 6;
    __shared__ double ws[4];

    double acc = 0.0;
    #pragma unroll
    for (int i = 0; i < GRID / 256; ++i)           // fixed index order
        acc += partials[tid + i * 256];
    #pragma unroll
    for (int d = 32; d > 0; d >>= 1) acc += __shfl_down(acc, d, 64);
    if (lane == 0) ws[wid] = acc;
    __syncthreads();
    if (tid == 0) {
        double s = ws[0] + ws[1] + ws[2] + ws[3];
        out[0] = (float)(-s / (double)NELEM);
    }
}

extern "C" void kernel_launch(void* const* d_in, const int* in_sizes, int n_in,
                              void* d_out, int out_size, void* d_ws, size_t ws_size,
                              hipStream_t stream)
{
    const float4* lam4  = (const float4*)d_in[0];
    const int4*   tgt4  = (const int4*)d_in[1];
    const int4*   risk4 = (const int4*)d_in[2];
    double* partials    = (double*)d_ws;   // 2048 * 8 B; every slot written every call
    float*  out         = (float*)d_out;

    loss_main<<<GRID, BLOCK, 0, stream>>>(lam4, tgt4, risk4, partials);
    loss_finalize<<<1, 256, 0, stream>>>(partials, out);
}

// Round 7
// 24.253 us; speedup vs baseline: 5.6118x; 1.0103x over previous
//
#include <hip/hip_runtime.h>
#include <math.h>

#define NELEM  8388608
#define GRID   2048
#define BLOCK  256
#define NVEC   (NELEM / 4)          // 2097152
#define STRIDE (GRID * BLOCK)       // 524288 -> exactly 4 vec4 groups per thread

// Two-kernel structure (R1/R6-proven). Changes vs R6:
//  - conflict-free LDS table: float cst[2][256], index r*256+t -> bank t&31
//    (random t spreads all 32 banks; R6's float2 layout hit only 8 banks,
//    SQ_LDS_BANK_CONFLICT 613K ~= 4.7 extra cy/gather)
//  - ll-coefficient computed in VALU (r ? t : -t(t+1)/2), only the constant
//    term is gathered
//  - all 12 global loads issued BEFORE the table build so lgammaf + scan
//    overlap load latency (barrier's vmcnt(0) completes them)
//  - __launch_bounds__(256,8) pins VGPR<=64 so all 8 blocks/CU co-reside
__global__ __launch_bounds__(BLOCK, 8) void loss_main(
    const float4* __restrict__ lam4,
    const int4*   __restrict__ tgt4,
    const int4*   __restrict__ risk4,
    double*       __restrict__ partials)
{
    __shared__ float  cst[512];     // cst[r*256 + t]
    __shared__ float  woff[4];
    __shared__ double wsum[4];

    const int tid  = threadIdx.x;
    const int lane = tid & 63;
    const int wid  = tid >> 6;
    const int base = blockIdx.x * BLOCK + tid;

    // ---- issue all 12 vector loads first (latency overlaps table build) ----
    float4 L0 = lam4[base];              int4 T0 = tgt4[base];              int4 R0 = risk4[base];
    float4 L1 = lam4[base + STRIDE];     int4 T1 = tgt4[base + STRIDE];     int4 R1 = risk4[base + STRIDE];
    float4 L2 = lam4[base + 2 * STRIDE]; int4 T2 = tgt4[base + 2 * STRIDE]; int4 R2 = risk4[base + 2 * STRIDE];
    float4 L3 = lam4[base + 3 * STRIDE]; int4 T3 = tgt4[base + 3 * STRIDE]; int4 R3 = risk4[base + 3 * STRIDE];

    // ---- build constant-term table (one t per thread) ----
    {
        float tf = (float)tid;
        float v  = lgammaf(tf + 1.0f);       // ln(t!)
        float scan = v;                       // inclusive wave scan
        #pragma unroll
        for (int d = 1; d < 64; d <<= 1) {
            float n = __shfl_up(scan, d, 64);
            if (lane >= d) scan += n;
        }
        if (lane == 63) woff[wid] = scan;
        __syncthreads();
        float off = 0.f;
        for (int w = 0; w < wid; ++w) off += woff[w];
        float csum = scan + off;              // cumsum of ln(j!) up to t
        cst[tid]       = (tf + 1.0f) + csum;  // r=0: (t+1) + csum[t]
        cst[256 + tid] = -v;                  // r=1: -lgamma(t+1)
    }
    __syncthreads();

    // ---- per element: val = a*la + b*ll + cst[r*256+t]
    //      a = r ? -1 : t+1 ;  b = r ? t : -t(t+1)/2  (VALU, no gather) ----
    double acc = 0.0;
    #define ONE(la_, t_, r_, g_) {                                   \
        float  la = (la_);                                           \
        int    t  = (t_);                                            \
        int    r  = (r_);                                            \
        float  tf = (float)t;                                        \
        float  a  = r ? -1.0f : (tf + 1.0f);                         \
        float  tt = fmaf(tf, tf, tf);       /* t(t+1) */             \
        float  b  = r ? tf : -0.5f * tt;                             \
        float  cc = cst[(r << 8) | t];                               \
        float  ll = __logf(la);                                      \
        g_ += fmaf(a, la, fmaf(b, ll, cc));                          \
    }
    #define GROUP(L, T, R) {                                         \
        float g = 0.f;                                               \
        ONE(L.x, T.x, R.x, g);                                       \
        ONE(L.y, T.y, R.y, g);                                       \
        ONE(L.z, T.z, R.z, g);                                       \
        ONE(L.w, T.w, R.w, g);                                       \
        acc += (double)g;                                            \
    }
    GROUP(L0, T0, R0);
    GROUP(L1, T1, R1);
    GROUP(L2, T2, R2);
    GROUP(L3, T3, R3);
    #undef GROUP
    #undef ONE

    // ---- block reduce (double, fixed order) ----
    #pragma unroll
    for (int d = 32; d > 0; d >>= 1) acc += __shfl_down(acc, d, 64);
    if (lane == 0) wsum[wid] = acc;
    __syncthreads();
    if (tid == 0)
        partials[blockIdx.x] = wsum[0] + wsum[1] + wsum[2] + wsum[3];
}

__global__ __launch_bounds__(256) void loss_finalize(
    const double* __restrict__ partials, float* __restrict__ out)
{
    const int tid  = threadIdx.x;
    const int lane = tid & 63;
    const int wid  = tid >> 6;
    __shared__ double ws[4];

    double acc = 0.0;
    #pragma unroll
    for (int i = 0; i < GRID / 256; ++i)           // fixed index order
        acc += partials[tid + i * 256];
    #pragma unroll
    for (int d = 32; d > 0; d >>= 1) acc += __shfl_down(acc, d, 64);
    if (lane == 0) ws[wid] = acc;
    __syncthreads();
    if (tid == 0) {
        double s = ws[0] + ws[1] + ws[2] + ws[3];
        out[0] = (float)(-s / (double)NELEM);
    }
}

extern "C" void kernel_launch(void* const* d_in, const int* in_sizes, int n_in,
                              void* d_out, int out_size, void* d_ws, size_t ws_size,
                              hipStream_t stream)
{
    const float4* lam4  = (const float4*)d_in[0];
    const int4*   tgt4  = (const int4*)d_in[1];
    const int4*   risk4 = (const int4*)d_in[2];
    double* partials    = (double*)d_ws;   // 2048 * 8 B; every slot written every call
    float*  out         = (float*)d_out;

    loss_main<<<GRID, BLOCK, 0, stream>>>(lam4, tgt4, risk4, partials);
    loss_finalize<<<1, 256, 0, stream>>>(partials, out);
}